// Round 5
// baseline (166.197 us; speedup 1.0000x reference)
//
#include <hip/hip_runtime.h>

typedef short short8 __attribute__((ext_vector_type(8)));
typedef float f32x4 __attribute__((ext_vector_type(4)));
typedef unsigned short u16;
typedef __attribute__((address_space(3))) unsigned lds_u32_t;
typedef __attribute__((address_space(1))) const unsigned glb_u32_t;

namespace {
constexpr int NIMG = 16;
constexpr int CIN  = 256;
constexpr int HIMG = 56;
constexpr int WIMG = 56;
constexpr int KOUT = 256;
constexpr int PIX  = HIMG * WIMG;          // 3136
constexpr int HPAD = 58;
constexpr int PP   = HPAD * HPAD;          // 3364
constexpr int TILES = 26;                  // 26*128 = 3328 >= 3246
constexpr int NX   = NIMG * CIN * PIX;     // 12,845,056
constexpr int NWEL = KOUT * CIN * 9;       // 589,824
constexpr int XQ_HALVES = NIMG * 32 * PP * 8;   // 13,778,944
constexpr int CHUNK = 8 * PIX;             // 25088 elements per (n, c-octet)
constexpr int XBLK = NIMG * 32;            // 512 fused x-quant blocks
constexpr int WB   = 64;                   // weight-quant blocks
}

// ---------------------------------------------------------------------------
// Fused BFP-quant + layout transform, one launch (unchanged from round 2):
//   blocks [0, XBLK)        : x -> xq2 chunked padded bf16 + halo
//   blocks [XBLK, XBLK+WB)  : weights -> wt3[rs][csp][kc][kout][8]
// ---------------------------------------------------------------------------
__global__ __launch_bounds__(256) void quant_fused(
        const float* __restrict__ x, u16* __restrict__ xq2,
        const float* __restrict__ wsrc, u16* __restrict__ wt3) {
    __shared__ u16 ot[CHUNK];                  // [cl*3136 + p] bf16, 50 KB
    const int b = blockIdx.x;
    const int t = threadIdx.x;

    if (b < XBLK) {
        const long s  = (long)b * CHUNK;       // first flat element of block
        const int  g0 = (int)(s / 36);
        const int  g1 = (int)((s + CHUNK - 1) / 36);

        // halo ring zero (independent of LDS; overlaps with loads)
        if (t < 228) {
            int ph, pw;
            if (t < 58)       { ph = 0;  pw = t; }
            else if (t < 116) { ph = 57; pw = t - 58; }
            else { int r = t - 116; ph = 1 + (r >> 1); pw = (r & 1) * 57; }
            *(uint4*)(xq2 + ((size_t)b * PP + ph * HPAD + pw) * 8) =
                make_uint4(0, 0, 0, 0);
        }

        for (int g = g0 + t; g <= g1; g += 256) {
            const long e0 = (long)g * 36;
            float v[36];
            if (e0 + 36 <= (long)NX) {
                const float4* p4 = (const float4*)(x + e0);
#pragma unroll
                for (int j = 0; j < 9; j++) {
                    float4 q4 = p4[j];
                    v[4*j+0] = q4.x; v[4*j+1] = q4.y;
                    v[4*j+2] = q4.z; v[4*j+3] = q4.w;
                }
            } else {                           // single global-tail group
                for (int j = 0; j < 36; j++)
                    v[j] = (e0 + j < (long)NX) ? x[e0 + j] : 0.f;
            }
            float ma = 0.f;
#pragma unroll
            for (int j = 0; j < 36; j++) ma = fmaxf(ma, fabsf(v[j]));
            float scale = 0.f, rinv = 0.f;
            if (ma != 0.f) {
                float e = floorf(log2f(ma));
                scale = exp2f(e - 7.f);
                rinv  = exp2f(7.f - e);
            }
            const long o = e0 - s;             // even; pairs never straddle
#pragma unroll
            for (int j = 0; j < 36; j += 2) {
                float qa = fminf(fmaxf(rintf(v[j]   * rinv), -128.f), 127.f) * scale;
                float qb = fminf(fmaxf(rintf(v[j+1] * rinv), -128.f), 127.f) * scale;
                uint pk = (__float_as_uint(qa) >> 16)
                        | ((__float_as_uint(qb) >> 16) << 16);
                long oo = o + j;
                if (oo >= 0 && oo < CHUNK)
                    *(uint*)&ot[oo] = pk;      // aligned b32 (oo even)
            }
        }
        __syncthreads();

        // interior write-out: coalesced short8, conflict-free scalar LDS reads
        for (int p = t; p < PIX; p += 256) {
            short8 o8;
#pragma unroll
            for (int cl = 0; cl < 8; cl++)
                o8[cl] = (short)ot[cl * PIX + p];
            int ph = p / WIMG + 1, pw = p % WIMG + 1;
            *(short8*)(xq2 + ((size_t)b * PP + ph * HPAD + pw) * 8) = o8;
        }
    } else {
        int g = (b - XBLK) * 256 + t;          // < 16384
        int base = g * 36;
        float v[36];
        const float4* p4 = (const float4*)(wsrc + base);
#pragma unroll
        for (int j = 0; j < 9; j++) {
            float4 tt = p4[j];
            v[4*j+0] = tt.x; v[4*j+1] = tt.y; v[4*j+2] = tt.z; v[4*j+3] = tt.w;
        }
        float ma = 0.f;
#pragma unroll
        for (int j = 0; j < 36; j++) ma = fmaxf(ma, fabsf(v[j]));
        float scale = 0.f, rinv = 0.f;
        if (ma != 0.f) {
            float e = floorf(log2f(ma));
            scale = exp2f(e - 7.f);
            rinv  = exp2f(7.f - e);
        }
        int k  = g >> 6;
        int c0 = (g & 63) * 4;
#pragma unroll
        for (int j = 0; j < 36; j++) {
            float q = rintf(v[j] * rinv);
            q = fminf(fmaxf(q, -128.f), 127.f) * scale;
            int c  = c0 + j / 9;
            int rs = j % 9;
            // wt3[rs][c>>6][(c>>3)&7][k][c&7]
            int idx = ((((rs * 4 + (c >> 6)) * 8 + ((c >> 3) & 7)) * KOUT) + k) * 8 + (c & 7);
            wt3[idx] = (u16)(__float_as_uint(q) >> 16);
        }
    }
}

// ---------------------------------------------------------------------------
// Implicit-GEMM conv, in-wave software-pipelined operand flow:
//   - A (weights): direct global->VGPR, depth-2 rotating banks (aA/aB);
//     bank (k&1) consumed at phase k, refilled with chunk c+2 right after
//     its MFMA cluster (compiler tracks the vmcnt dependency).
//   - B (activations): 32 KB per-csp pixel window in LDS (as round 4), but
//     fragments are register double-buffered (pA/pB): phase k issues phase
//     k+1's 4 ds_read_b128 BEFORE its own MFMA cluster, so ds_read issue +
//     latency hide under the 80-cyc MFMA block of the same wave.
//   - per-phase sched_barrier(0) pins the [issue | MFMA] pipeline the
//     compiler's register-pressure heuristic refused to build (R4: VGPR 92).
//   - chunk order (csp -> rs -> sub) and MFMA operand sequence identical to
//     previous rounds -> bit-exact output.
// ---------------------------------------------------------------------------
#define LOADA(dst_, c_)                                                        \
    {                                                                          \
        const int csp_ = (c_) / 18;                                            \
        const int rsk_ = ((c_) % 18) / 2;                                      \
        const int sub_ = (c_) & 1;                                             \
        const u16* ap_ = wt3 + (rsk_ * 4 + csp_) * 16384 + sub_ * 8192;        \
        _Pragma("unroll")                                                      \
        for (int i_ = 0; i_ < 4; i_++)                                         \
            dst_[i_] = *(const short8*)(ap_ + aOff + i_ * 128);                \
    }

#define READB(dst_, kk_)                                                       \
    {                                                                          \
        const int rs_  = (kk_) >> 1;                                           \
        const int sub_ = (kk_) & 1;                                            \
        const int doff_ = (rs_ / 3) * HPAD + (rs_ % 3);                        \
        _Pragma("unroll")                                                      \
        for (int j_ = 0; j_ < 4; j_++)                                         \
            dst_[j_] = *(const short8*)(lB + (sub_ * 4 + fkk) * 2048           \
                                        + (doff_ + bcol + j_ * 16) * 8);       \
    }

__global__ __launch_bounds__(256) void conv_kernel(
        const u16* __restrict__ xq2, const u16* __restrict__ wt3,
        const float* __restrict__ bias, float* __restrict__ out) {
    __shared__ u16 lB[16384];   // [oct(8)][pix(256)][8] window = 32 KB

    const int tid  = threadIdx.x;
    const int lane = tid & 63;
    const int wv   = tid >> 6;
    const int bx   = blockIdx.x;
    const int n    = bx / TILES;
    const int t0   = (bx % TILES) * 128;
    const int k0   = blockIdx.y * 128;

    const int frow = lane & 15;
    const int fkk  = lane >> 4;
    // A-fragment per-lane offset (halves): kc-in-sub = fkk, kout row
    const int aOff = fkk * 2048 + (k0 + (wv >> 1) * 64 + frow) * 8;
    // B-fragment per-lane column base within window
    const int bcol = (wv & 1) * 64 + frow;

    f32x4 acc[4][4] = {};
    short8 aA[4], aB[4];                 // A banks: phase parity k&1
    short8 pA[4], pB[4];                 // B frag banks: phase parity k&1

    // prologue: A for chunks 0,1
    LOADA(aA, 0);
    LOADA(aB, 1);

#pragma unroll
    for (int s = 0; s < 4; s++) {
        __builtin_amdgcn_s_barrier();    // all waves done reading window s-1
        // stage window s: 8 x 1KB contiguous global_load_lds per wave
#pragma unroll
        for (int l = 0; l < 8; l++) {
            const int oct = wv * 2 + (l >> 2);
            const int q   = l & 3;
            __builtin_amdgcn_global_load_lds(
                (glb_u32_t*)(xq2 + ((size_t)(n * 32 + s * 8 + oct) * PP
                                    + t0 + q * 64 + lane) * 8),
                (lds_u32_t*)(lB + oct * 2048 + q * 512 + lane * 8),
                16, 0, 0);
        }
        asm volatile("s_waitcnt vmcnt(0)" ::: "memory");   // window landed
        __builtin_amdgcn_s_barrier();    // ... for ALL waves
        __builtin_amdgcn_sched_barrier(0);

        READB(pA, 0);                    // prime B pipeline for phase 0

#pragma unroll
        for (int k = 0; k < 18; k++) {
            const int c = 18 * s + k;

            // issue phase k+1's B frags into the other bank (under MFMA)
            if (k < 17) {
                if (((k + 1) & 1) == 0) READB(pA, k + 1)
                else                    READB(pB, k + 1)
            }
            __builtin_amdgcn_sched_barrier(0);   // pin: issue before MFMA

            __builtin_amdgcn_s_setprio(1);
#pragma unroll
            for (int i = 0; i < 4; i++)
#pragma unroll
                for (int j = 0; j < 4; j++)
                    acc[i][j] = __builtin_amdgcn_mfma_f32_16x16x32_bf16(
                        (k & 1) ? aB[i] : aA[i],
                        (k & 1) ? pB[j] : pA[j],
                        acc[i][j], 0, 0, 0);
            __builtin_amdgcn_s_setprio(0);

            // refill the A bank just consumed (WAR tracked by compiler;
            // issue lands in the MFMA shadow, used at phase k+2)
            if (c + 2 < 72) {
                if ((k & 1) == 0) LOADA(aA, c + 2)
                else              LOADA(aB, c + 2)
            }
        }
    }

    // epilogue: rows = outch, cols = padded pixel t0+col; skip invalid cols
    const int kbase = k0 + (wv >> 1) * 64 + fkk * 4;
    const int mbase = (wv & 1) * 64 + frow;
#pragma unroll
    for (int j = 0; j < 4; j++) {
        int ppp = t0 + mbase + j * 16;
        int h = ppp / HPAD, w = ppp % HPAD;
        if (w < WIMG && h < HIMG) {
            float* ob = out + (size_t)n * KOUT * PIX + h * WIMG + w;
#pragma unroll
            for (int i = 0; i < 4; i++) {
                int kch = kbase + i * 16;
#pragma unroll
                for (int r = 0; r < 4; r++)
                    ob[(size_t)(kch + r) * PIX] = acc[i][j][r] + bias[kch + r];
            }
        }
    }
}

// ---------------------------------------------------------------------------
extern "C" void kernel_launch(void* const* d_in, const int* in_sizes, int n_in,
                              void* d_out, int out_size, void* d_ws, size_t ws_size,
                              hipStream_t stream) {
    const float* x   = (const float*)d_in[0];
    const float* wgt = (const float*)d_in[1];
    const float* bs  = (const float*)d_in[2];
    float* out = (float*)d_out;

    u16* xq2 = (u16*)d_ws;                 // 27.56 MB chunked padded activations
    u16* wt3 = xq2 + XQ_HALVES;            // 1.18 MB  staged weight layout

    quant_fused<<<XBLK + WB, 256, 0, stream>>>(x, xq2, wgt, wt3);
    conv_kernel<<<dim3(NIMG * TILES, 2), 256, 0, stream>>>(xq2, wt3, bs, out);
}

// Round 6
// 158.872 us; speedup vs baseline: 1.0461x; 1.0461x over previous
//
#include <hip/hip_runtime.h>

typedef short short8 __attribute__((ext_vector_type(8)));
typedef float f32x4 __attribute__((ext_vector_type(4)));
typedef unsigned short u16;
typedef __attribute__((address_space(3))) unsigned lds_u32_t;
typedef __attribute__((address_space(1))) const unsigned glb_u32_t;

namespace {
constexpr int NIMG = 16;
constexpr int CIN  = 256;
constexpr int HIMG = 56;
constexpr int WIMG = 56;
constexpr int KOUT = 256;
constexpr int PIX  = HIMG * WIMG;          // 3136
constexpr int HPAD = 58;
constexpr int PP   = HPAD * HPAD;          // 3364
constexpr int TILES = 26;                  // 26*128 = 3328 >= 3246
constexpr int NX   = NIMG * CIN * PIX;     // 12,845,056
constexpr int NWEL = KOUT * CIN * 9;       // 589,824
constexpr int XQ_HALVES = NIMG * 32 * PP * 8;   // 13,778,944
constexpr int CHUNK = 8 * PIX;             // 25088 elements per (n, c-octet)
constexpr int XBLK = NIMG * 32;            // 512 fused x-quant blocks
constexpr int WB   = 64;                   // weight-quant blocks
constexpr int NWG  = NIMG * TILES * 2;     // 1664 conv work items (8 | 1664)
constexpr int CPX  = NWG / 8;              // 208 work items per XCD chunk
}

// ---------------------------------------------------------------------------
// Fused BFP-quant + layout transform, one launch (unchanged from round 2):
//   blocks [0, XBLK)        : x -> xq2 chunked padded bf16 + halo
//   blocks [XBLK, XBLK+WB)  : weights -> wt3[rs][csp][kc][kout][8]
// ---------------------------------------------------------------------------
__global__ __launch_bounds__(256) void quant_fused(
        const float* __restrict__ x, u16* __restrict__ xq2,
        const float* __restrict__ wsrc, u16* __restrict__ wt3) {
    __shared__ u16 ot[CHUNK];                  // [cl*3136 + p] bf16, 50 KB
    const int b = blockIdx.x;
    const int t = threadIdx.x;

    if (b < XBLK) {
        const long s  = (long)b * CHUNK;       // first flat element of block
        const int  g0 = (int)(s / 36);
        const int  g1 = (int)((s + CHUNK - 1) / 36);

        // halo ring zero (independent of LDS; overlaps with loads)
        if (t < 228) {
            int ph, pw;
            if (t < 58)       { ph = 0;  pw = t; }
            else if (t < 116) { ph = 57; pw = t - 58; }
            else { int r = t - 116; ph = 1 + (r >> 1); pw = (r & 1) * 57; }
            *(uint4*)(xq2 + ((size_t)b * PP + ph * HPAD + pw) * 8) =
                make_uint4(0, 0, 0, 0);
        }

        for (int g = g0 + t; g <= g1; g += 256) {
            const long e0 = (long)g * 36;
            float v[36];
            if (e0 + 36 <= (long)NX) {
                const float4* p4 = (const float4*)(x + e0);
#pragma unroll
                for (int j = 0; j < 9; j++) {
                    float4 q4 = p4[j];
                    v[4*j+0] = q4.x; v[4*j+1] = q4.y;
                    v[4*j+2] = q4.z; v[4*j+3] = q4.w;
                }
            } else {                           // single global-tail group
                for (int j = 0; j < 36; j++)
                    v[j] = (e0 + j < (long)NX) ? x[e0 + j] : 0.f;
            }
            float ma = 0.f;
#pragma unroll
            for (int j = 0; j < 36; j++) ma = fmaxf(ma, fabsf(v[j]));
            float scale = 0.f, rinv = 0.f;
            if (ma != 0.f) {
                float e = floorf(log2f(ma));
                scale = exp2f(e - 7.f);
                rinv  = exp2f(7.f - e);
            }
            const long o = e0 - s;             // even; pairs never straddle
#pragma unroll
            for (int j = 0; j < 36; j += 2) {
                float qa = fminf(fmaxf(rintf(v[j]   * rinv), -128.f), 127.f) * scale;
                float qb = fminf(fmaxf(rintf(v[j+1] * rinv), -128.f), 127.f) * scale;
                uint pk = (__float_as_uint(qa) >> 16)
                        | ((__float_as_uint(qb) >> 16) << 16);
                long oo = o + j;
                if (oo >= 0 && oo < CHUNK)
                    *(uint*)&ot[oo] = pk;      // aligned b32 (oo even)
            }
        }
        __syncthreads();

        // interior write-out: coalesced short8, conflict-free scalar LDS reads
        for (int p = t; p < PIX; p += 256) {
            short8 o8;
#pragma unroll
            for (int cl = 0; cl < 8; cl++)
                o8[cl] = (short)ot[cl * PIX + p];
            int ph = p / WIMG + 1, pw = p % WIMG + 1;
            *(short8*)(xq2 + ((size_t)b * PP + ph * HPAD + pw) * 8) = o8;
        }
    } else {
        int g = (b - XBLK) * 256 + t;          // < 16384
        int base = g * 36;
        float v[36];
        const float4* p4 = (const float4*)(wsrc + base);
#pragma unroll
        for (int j = 0; j < 9; j++) {
            float4 tt = p4[j];
            v[4*j+0] = tt.x; v[4*j+1] = tt.y; v[4*j+2] = tt.z; v[4*j+3] = tt.w;
        }
        float ma = 0.f;
#pragma unroll
        for (int j = 0; j < 36; j++) ma = fmaxf(ma, fabsf(v[j]));
        float scale = 0.f, rinv = 0.f;
        if (ma != 0.f) {
            float e = floorf(log2f(ma));
            scale = exp2f(e - 7.f);
            rinv  = exp2f(7.f - e);
        }
        int k  = g >> 6;
        int c0 = (g & 63) * 4;
#pragma unroll
        for (int j = 0; j < 36; j++) {
            float q = rintf(v[j] * rinv);
            q = fminf(fmaxf(q, -128.f), 127.f) * scale;
            int c  = c0 + j / 9;
            int rs = j % 9;
            // wt3[rs][c>>6][(c>>3)&7][k][c&7]
            int idx = ((((rs * 4 + (c >> 6)) * 8 + ((c >> 3) & 7)) * KOUT) + k) * 8 + (c & 7);
            wt3[idx] = (u16)(__float_as_uint(q) >> 16);
        }
    }
}

// ---------------------------------------------------------------------------
// Implicit-GEMM conv:
//   - A (weights): direct global->VGPR, depth-3 rotating banks; plain loads,
//     compiler-managed waitcnt (no asm fences -> scheduler free to pipeline).
//   - B (activations): 32 KB per-csp pixel window in LDS; 18 fence-free
//     phases per window -> compiler software-pipelines ds_reads across
//     phases itself (R4/R5 lesson: manual vmcnt/sched_barrier fences only
//     FORBID this and were neutral-to-negative).
//   - window boundaries: __syncthreads() (its vmcnt(0)+lgkmcnt(0) drain
//     covers global_load_lds completion).
//   - grid: 1664 flat blocks, bijective XCD swizzle (1664 = 8*208).
//     work = (bx%8)*208 + bx/8; consecutive work items = the two k0-halves
//     of one tile (identical B window) then adjacent tiles (50% window
//     overlap) -> co-resident on one XCD's L2 -> window re-fetch = L2 hit.
//   - all partial sums exactly representable (8-bit mantissas x pow2
//     scales), so accumulation-order freedom is bit-safe (absmax 0.0).
// ---------------------------------------------------------------------------
#define LOADA(dst_, c_)                                                        \
    {                                                                          \
        const int csp_ = (c_) / 18;                                            \
        const int rsk_ = ((c_) % 18) / 2;                                      \
        const int sub_ = (c_) & 1;                                             \
        const u16* ap_ = wt3 + (rsk_ * 4 + csp_) * 16384 + sub_ * 8192;        \
        _Pragma("unroll")                                                      \
        for (int i_ = 0; i_ < 4; i_++)                                         \
            dst_[i_] = *(const short8*)(ap_ + aOff + i_ * 128);                \
    }

__global__ __launch_bounds__(256) void conv_kernel(
        const u16* __restrict__ xq2, const u16* __restrict__ wt3,
        const float* __restrict__ bias, float* __restrict__ out) {
    __shared__ u16 lB[16384];   // [oct(8)][pix(256)][8] window = 32 KB

    const int tid  = threadIdx.x;
    const int lane = tid & 63;
    const int wv   = tid >> 6;

    // bijective XCD swizzle: 1664 = 8 * 208
    const int work = ((int)blockIdx.x & 7) * CPX + ((int)blockIdx.x >> 3);
    const int k0   = (work & 1) * 128;
    const int pair = work >> 1;                // [0, 832)
    const int n    = pair / TILES;
    const int t0   = (pair % TILES) * 128;

    const int frow = lane & 15;
    const int fkk  = lane >> 4;
    // A-fragment per-lane offset (halves): kc-in-sub = fkk, kout row
    const int aOff = fkk * 2048 + (k0 + (wv >> 1) * 64 + frow) * 8;
    // B-fragment per-lane column base within window
    const int bcol = (wv & 1) * 64 + frow;

    f32x4 acc[4][4] = {};
    short8 a0[4], a1[4], a2[4];          // rotating A banks (chunk c%3)

    // prologue: A for chunks 0,1,2
    LOADA(a0, 0);
    LOADA(a1, 1);
    LOADA(a2, 2);

#pragma unroll
    for (int s = 0; s < 4; s++) {
        __syncthreads();                 // all waves done reading window s-1
        // stage window s: 8 x 1KB contiguous global_load_lds per wave
#pragma unroll
        for (int l = 0; l < 8; l++) {
            const int oct = wv * 2 + (l >> 2);
            const int q   = l & 3;
            __builtin_amdgcn_global_load_lds(
                (glb_u32_t*)(xq2 + ((size_t)(n * 32 + s * 8 + oct) * PP
                                    + t0 + q * 64 + lane) * 8),
                (lds_u32_t*)(lB + oct * 2048 + q * 512 + lane * 8),
                16, 0, 0);
        }
        __syncthreads();                 // vmcnt(0)+lgkmcnt(0) drain + barrier

#pragma unroll
        for (int k = 0; k < 18; k++) {
            const int c   = 18 * s + k;
            const int rs  = k >> 1;
            const int sub = k & 1;
            const int doff = (rs / 3) * HPAD + (rs % 3);

            short8 bf[4];
#pragma unroll
            for (int j = 0; j < 4; j++)
                bf[j] = *(const short8*)(lB + (sub * 4 + fkk) * 2048
                                         + (doff + bcol + j * 16) * 8);

            __builtin_amdgcn_s_setprio(1);
#pragma unroll
            for (int i = 0; i < 4; i++)
#pragma unroll
                for (int j = 0; j < 4; j++)
                    acc[i][j] = __builtin_amdgcn_mfma_f32_16x16x32_bf16(
                        (k % 3 == 0) ? a0[i] : (k % 3 == 1) ? a1[i] : a2[i],
                        bf[j], acc[i][j], 0, 0, 0);
            __builtin_amdgcn_s_setprio(0);

            if (c + 3 < 72) {            // refill the bank just consumed
                if (k % 3 == 0)      LOADA(a0, c + 3)
                else if (k % 3 == 1) LOADA(a1, c + 3)
                else                 LOADA(a2, c + 3)
            }
        }
    }

    // epilogue: rows = outch, cols = padded pixel t0+col; skip invalid cols
    const int kbase = k0 + (wv >> 1) * 64 + fkk * 4;
    const int mbase = (wv & 1) * 64 + frow;
#pragma unroll
    for (int j = 0; j < 4; j++) {
        int ppp = t0 + mbase + j * 16;
        int h = ppp / HPAD, w = ppp % HPAD;
        if (w < WIMG && h < HIMG) {
            float* ob = out + (size_t)n * KOUT * PIX + h * WIMG + w;
#pragma unroll
            for (int i = 0; i < 4; i++) {
                int kch = kbase + i * 16;
#pragma unroll
                for (int r = 0; r < 4; r++)
                    ob[(size_t)(kch + r) * PIX] = acc[i][j][r] + bias[kch + r];
            }
        }
    }
}

// ---------------------------------------------------------------------------
extern "C" void kernel_launch(void* const* d_in, const int* in_sizes, int n_in,
                              void* d_out, int out_size, void* d_ws, size_t ws_size,
                              hipStream_t stream) {
    const float* x   = (const float*)d_in[0];
    const float* wgt = (const float*)d_in[1];
    const float* bs  = (const float*)d_in[2];
    float* out = (float*)d_out;

    u16* xq2 = (u16*)d_ws;                 // 27.56 MB chunked padded activations
    u16* wt3 = xq2 + XQ_HALVES;            // 1.18 MB  staged weight layout

    quant_fused<<<XBLK + WB, 256, 0, stream>>>(x, xq2, wgt, wt3);
    conv_kernel<<<NWG, 256, 0, stream>>>(xq2, wt3, bs, out);
}

// Round 7
// 155.866 us; speedup vs baseline: 1.0663x; 1.0193x over previous
//
#include <hip/hip_runtime.h>

typedef short short8 __attribute__((ext_vector_type(8)));
typedef float f32x4 __attribute__((ext_vector_type(4)));
typedef unsigned short u16;
typedef __attribute__((address_space(3))) unsigned lds_u32_t;
typedef __attribute__((address_space(1))) const unsigned glb_u32_t;

namespace {
constexpr int NIMG = 16;
constexpr int CIN  = 256;
constexpr int HIMG = 56;
constexpr int WIMG = 56;
constexpr int KOUT = 256;
constexpr int PIX  = HIMG * WIMG;          // 3136
constexpr int HPAD = 58;
constexpr int PP   = HPAD * HPAD;          // 3364
constexpr int TILES = 26;                  // 26*128 = 3328 >= 3246
constexpr int NX   = NIMG * CIN * PIX;     // 12,845,056
constexpr int NWEL = KOUT * CIN * 9;       // 589,824
constexpr int XQ_HALVES = NIMG * 32 * PP * 8;   // 13,778,944
constexpr int CHUNK = 8 * PIX;             // 25088 elements per (n, c-octet)
constexpr int XBLK = NIMG * 32;            // 512 fused x-quant blocks
constexpr int WB   = 64;                   // weight-quant blocks
constexpr int NWG  = NIMG * TILES * 4;     // 1664 conv blocks (8 | 1664)
constexpr int CPX  = NWG / 8;              // 208 blocks per XCD chunk
}

// ---------------------------------------------------------------------------
// Fused BFP-quant + layout transform, one launch (unchanged from round 2):
//   blocks [0, XBLK)        : x -> xq2 chunked padded bf16 + halo
//   blocks [XBLK, XBLK+WB)  : weights -> wt3[rs][csp][kc][kout][8]
// ---------------------------------------------------------------------------
__global__ __launch_bounds__(256) void quant_fused(
        const float* __restrict__ x, u16* __restrict__ xq2,
        const float* __restrict__ wsrc, u16* __restrict__ wt3) {
    __shared__ u16 ot[CHUNK];                  // [cl*3136 + p] bf16, 50 KB
    const int b = blockIdx.x;
    const int t = threadIdx.x;

    if (b < XBLK) {
        const long s  = (long)b * CHUNK;       // first flat element of block
        const int  g0 = (int)(s / 36);
        const int  g1 = (int)((s + CHUNK - 1) / 36);

        // halo ring zero (independent of LDS; overlaps with loads)
        if (t < 228) {
            int ph, pw;
            if (t < 58)       { ph = 0;  pw = t; }
            else if (t < 116) { ph = 57; pw = t - 58; }
            else { int r = t - 116; ph = 1 + (r >> 1); pw = (r & 1) * 57; }
            *(uint4*)(xq2 + ((size_t)b * PP + ph * HPAD + pw) * 8) =
                make_uint4(0, 0, 0, 0);
        }

        for (int g = g0 + t; g <= g1; g += 256) {
            const long e0 = (long)g * 36;
            float v[36];
            if (e0 + 36 <= (long)NX) {
                const float4* p4 = (const float4*)(x + e0);
#pragma unroll
                for (int j = 0; j < 9; j++) {
                    float4 q4 = p4[j];
                    v[4*j+0] = q4.x; v[4*j+1] = q4.y;
                    v[4*j+2] = q4.z; v[4*j+3] = q4.w;
                }
            } else {                           // single global-tail group
                for (int j = 0; j < 36; j++)
                    v[j] = (e0 + j < (long)NX) ? x[e0 + j] : 0.f;
            }
            float ma = 0.f;
#pragma unroll
            for (int j = 0; j < 36; j++) ma = fmaxf(ma, fabsf(v[j]));
            float scale = 0.f, rinv = 0.f;
            if (ma != 0.f) {
                float e = floorf(log2f(ma));
                scale = exp2f(e - 7.f);
                rinv  = exp2f(7.f - e);
            }
            const long o = e0 - s;             // even; pairs never straddle
#pragma unroll
            for (int j = 0; j < 36; j += 2) {
                float qa = fminf(fmaxf(rintf(v[j]   * rinv), -128.f), 127.f) * scale;
                float qb = fminf(fmaxf(rintf(v[j+1] * rinv), -128.f), 127.f) * scale;
                uint pk = (__float_as_uint(qa) >> 16)
                        | ((__float_as_uint(qb) >> 16) << 16);
                long oo = o + j;
                if (oo >= 0 && oo < CHUNK)
                    *(uint*)&ot[oo] = pk;      // aligned b32 (oo even)
            }
        }
        __syncthreads();

        // interior write-out: coalesced short8, conflict-free scalar LDS reads
        for (int p = t; p < PIX; p += 256) {
            short8 o8;
#pragma unroll
            for (int cl = 0; cl < 8; cl++)
                o8[cl] = (short)ot[cl * PIX + p];
            int ph = p / WIMG + 1, pw = p % WIMG + 1;
            *(short8*)(xq2 + ((size_t)b * PP + ph * HPAD + pw) * 8) = o8;
        }
    } else {
        int g = (b - XBLK) * 256 + t;          // < 16384
        int base = g * 36;
        float v[36];
        const float4* p4 = (const float4*)(wsrc + base);
#pragma unroll
        for (int j = 0; j < 9; j++) {
            float4 tt = p4[j];
            v[4*j+0] = tt.x; v[4*j+1] = tt.y; v[4*j+2] = tt.z; v[4*j+3] = tt.w;
        }
        float ma = 0.f;
#pragma unroll
        for (int j = 0; j < 36; j++) ma = fmaxf(ma, fabsf(v[j]));
        float scale = 0.f, rinv = 0.f;
        if (ma != 0.f) {
            float e = floorf(log2f(ma));
            scale = exp2f(e - 7.f);
            rinv  = exp2f(7.f - e);
        }
        int k  = g >> 6;
        int c0 = (g & 63) * 4;
#pragma unroll
        for (int j = 0; j < 36; j++) {
            float q = rintf(v[j] * rinv);
            q = fminf(fmaxf(q, -128.f), 127.f) * scale;
            int c  = c0 + j / 9;
            int rs = j % 9;
            // wt3[rs][c>>6][(c>>3)&7][k][c&7]
            int idx = ((((rs * 4 + (c >> 6)) * 8 + ((c >> 3) & 7)) * KOUT) + k) * 8 + (c & 7);
            wt3[idx] = (u16)(__float_as_uint(q) >> 16);
        }
    }
}

// ---------------------------------------------------------------------------
// Implicit-GEMM conv, occupancy-doubled variant:
//   - block tile 64 kout x 128 cols (was 128x128); wave = 32 kout x 64 cols,
//     acc[2][4] = 32 AGPR. Total regs ~95-100, pinned <=128 via
//     __launch_bounds__(256,4) -> 16 waves/CU (4 resident blocks, was 2 at
//     156 regs). R6 evidence: matrix pipes only ~12-15% issue-busy with
//     nothing else saturated -> latency-bound from insufficient residency.
//   - grid 1664 = 16 img x 26 tiles x 4 kout-quarters; bijective XCD
//     swizzle (1664 = 8*208); the 4 kq of one tile are consecutive -> share
//     the identical B window via L2.
//   - all traffic ratios unchanged vs R6: A bytes/FLOP same (A per chunk
//     scales with kout), B window 32 KB per block same, ds_read:MFMA same.
//   - fence-free 18-chunk window body (R5/R6 lesson), __syncthreads()
//     window boundaries, setprio around MFMA, depth-3 A banks.
//   - accumulation sequence per output unchanged -> bit-exact.
// ---------------------------------------------------------------------------
#define LOADA(dst_, c_)                                                        \
    {                                                                          \
        const int csp_ = (c_) / 18;                                            \
        const int rsk_ = ((c_) % 18) / 2;                                      \
        const int sub_ = (c_) & 1;                                             \
        const u16* ap_ = wt3 + (rsk_ * 4 + csp_) * 16384 + sub_ * 8192;        \
        _Pragma("unroll")                                                      \
        for (int i_ = 0; i_ < 2; i_++)                                         \
            dst_[i_] = *(const short8*)(ap_ + aOff + i_ * 128);                \
    }

__global__ __launch_bounds__(256, 4) void conv_kernel(
        const u16* __restrict__ xq2, const u16* __restrict__ wt3,
        const float* __restrict__ bias, float* __restrict__ out) {
    __shared__ u16 lB[16384];   // [oct(8)][pix(256)][8] window = 32 KB

    const int tid  = threadIdx.x;
    const int lane = tid & 63;
    const int wv   = tid >> 6;

    // bijective XCD swizzle: 1664 = 8 * 208
    const int work = ((int)blockIdx.x & 7) * CPX + ((int)blockIdx.x >> 3);
    const int kq   = work & 3;                 // kout quarter (shares window)
    const int pair = work >> 2;                // [0, 416)
    const int n    = pair / TILES;
    const int t0   = (pair % TILES) * 128;

    const int frow = lane & 15;
    const int fkk  = lane >> 4;
    // A-fragment per-lane offset (halves): kc-in-sub = fkk, kout row
    const int aOff = fkk * 2048 + (kq * 64 + (wv >> 1) * 32 + frow) * 8;
    // B-fragment per-lane column base within window
    const int bcol = (wv & 1) * 64 + frow;

    f32x4 acc[2][4] = {};
    short8 a0[2], a1[2], a2[2];          // rotating A banks (chunk c%3)

    // prologue: A for chunks 0,1,2
    LOADA(a0, 0);
    LOADA(a1, 1);
    LOADA(a2, 2);

#pragma unroll
    for (int s = 0; s < 4; s++) {
        __syncthreads();                 // all waves done reading window s-1
        // stage window s: 8 x 1KB contiguous global_load_lds per wave
#pragma unroll
        for (int l = 0; l < 8; l++) {
            const int oct = wv * 2 + (l >> 2);
            const int q   = l & 3;
            __builtin_amdgcn_global_load_lds(
                (glb_u32_t*)(xq2 + ((size_t)(n * 32 + s * 8 + oct) * PP
                                    + t0 + q * 64 + lane) * 8),
                (lds_u32_t*)(lB + oct * 2048 + q * 512 + lane * 8),
                16, 0, 0);
        }
        __syncthreads();                 // vmcnt(0)+lgkmcnt(0) drain + barrier

#pragma unroll
        for (int k = 0; k < 18; k++) {
            const int c   = 18 * s + k;
            const int rs  = k >> 1;
            const int sub = k & 1;
            const int doff = (rs / 3) * HPAD + (rs % 3);

            short8 bf[4];
#pragma unroll
            for (int j = 0; j < 4; j++)
                bf[j] = *(const short8*)(lB + (sub * 4 + fkk) * 2048
                                         + (doff + bcol + j * 16) * 8);

            __builtin_amdgcn_s_setprio(1);
#pragma unroll
            for (int i = 0; i < 2; i++)
#pragma unroll
                for (int j = 0; j < 4; j++)
                    acc[i][j] = __builtin_amdgcn_mfma_f32_16x16x32_bf16(
                        (k % 3 == 0) ? a0[i] : (k % 3 == 1) ? a1[i] : a2[i],
                        bf[j], acc[i][j], 0, 0, 0);
            __builtin_amdgcn_s_setprio(0);

            if (c + 3 < 72) {            // refill the bank just consumed
                if (k % 3 == 0)      LOADA(a0, c + 3)
                else if (k % 3 == 1) LOADA(a1, c + 3)
                else                 LOADA(a2, c + 3)
            }
        }
    }

    // epilogue: rows = outch, cols = padded pixel t0+col; skip invalid cols
    const int kbase = kq * 64 + (wv >> 1) * 32 + fkk * 4;
    const int mbase = (wv & 1) * 64 + frow;
#pragma unroll
    for (int j = 0; j < 4; j++) {
        int ppp = t0 + mbase + j * 16;
        int h = ppp / HPAD, w = ppp % HPAD;
        if (w < WIMG && h < HIMG) {
            float* ob = out + (size_t)n * KOUT * PIX + h * WIMG + w;
#pragma unroll
            for (int i = 0; i < 2; i++) {
                int kch = kbase + i * 16;
#pragma unroll
                for (int r = 0; r < 4; r++)
                    ob[(size_t)(kch + r) * PIX] = acc[i][j][r] + bias[kch + r];
            }
        }
    }
}

// ---------------------------------------------------------------------------
extern "C" void kernel_launch(void* const* d_in, const int* in_sizes, int n_in,
                              void* d_out, int out_size, void* d_ws, size_t ws_size,
                              hipStream_t stream) {
    const float* x   = (const float*)d_in[0];
    const float* wgt = (const float*)d_in[1];
    const float* bs  = (const float*)d_in[2];
    float* out = (float*)d_out;

    u16* xq2 = (u16*)d_ws;                 // 27.56 MB chunked padded activations
    u16* wt3 = xq2 + XQ_HALVES;            // 1.18 MB  staged weight layout

    quant_fused<<<XBLK + WB, 256, 0, stream>>>(x, xq2, wgt, wt3);
    conv_kernel<<<NWG, 256, 0, stream>>>(xq2, wt3, bs, out);
}